// Round 18
// baseline (91.170 us; speedup 1.0000x reference)
//
#include <hip/hip_runtime.h>
#include <hip/hip_bf16.h>
#include <cstdint>

#define L_SEQ 1024
#define HID_DIM 512
#define N_HEADS 8
#define HEAD_DIM 64
#define BATCH 8

typedef __attribute__((ext_vector_type(8))) short bf16x8;
typedef __attribute__((ext_vector_type(4))) float f32x4;

__device__ __forceinline__ ushort f2bf(float v) {
  __hip_bfloat16 hb = __float2bfloat16(v);
  return *(ushort*)&hb;
}

// Fused: blocks <2560 convert f32->bf16 (x then Wq,Wk,Wv,Wo); blocks >=2560
// compute lens[b] (layout-detecting padding_mask row count, see round 3).
__global__ __launch_bounds__(256)
void prep_lens(const float* __restrict__ x, const float* __restrict__ Wq,
               const float* __restrict__ Wk, const float* __restrict__ Wv,
               const float* __restrict__ Wo, const uint8_t* __restrict__ pm,
               ushort* __restrict__ dst, int* __restrict__ lens) {
  if (blockIdx.x >= 2560) {
    __shared__ int flag;
    __shared__ int part[256];
    const int b = blockIdx.x - 2560, tid = threadIdx.x;
    if (tid == 0) flag = 0;
    __syncthreads();
    const unsigned* pw = (const unsigned*)pm;
    unsigned any = 0;
    for (int i = tid; i < 2048; i += 256) any |= (pw[i] > 1u);
    if (any) flag = 1;
    __syncthreads();
    int c = 0;
    if (flag) {
      unsigned v = pw[b * 256 + tid];
      c = (int)((v & 0xFFu) == 0) + (int)(((v >> 8) & 0xFFu) == 0) +
          (int)(((v >> 16) & 0xFFu) == 0) + (int)(((v >> 24) & 0xFFu) == 0);
    } else {
      const int* pi = (const int*)pm;
      c = (int)(pi[b * 1024 + tid * 4 + 0] == 0) + (int)(pi[b * 1024 + tid * 4 + 1] == 0) +
          (int)(pi[b * 1024 + tid * 4 + 2] == 0) + (int)(pi[b * 1024 + tid * 4 + 3] == 0);
    }
    part[tid] = c;
    __syncthreads();
    for (int s = 128; s > 0; s >>= 1) {
      if (tid < s) part[tid] += part[tid + s];
      __syncthreads();
    }
    if (tid == 0) lens[b] = part[0];
    return;
  }
  const size_t gid = (size_t)blockIdx.x * 256 + threadIdx.x;
  const size_t e = gid * 8;
  const float* src;
  size_t loc;
  if (e < 4194304) {
    src = x; loc = e;
  } else {
    const size_t r = e - 4194304;
    const int wsel = (int)(r >> 18);
    loc = r & 262143;
    src = (wsel == 0) ? Wq : (wsel == 1) ? Wk : (wsel == 2) ? Wv : Wo;
  }
  float4 v0 = *(const float4*)(src + loc);
  float4 v1 = *(const float4*)(src + loc + 4);
  ushort u[8];
  u[0] = f2bf(v0.x); u[1] = f2bf(v0.y); u[2] = f2bf(v0.z); u[3] = f2bf(v0.w);
  u[4] = f2bf(v1.x); u[5] = f2bf(v1.y); u[6] = f2bf(v1.z); u[7] = f2bf(v1.w);
  *(uint4*)(dst + e) = *(uint4*)u;
}

// ---------------------------------------------------------------------------
// LDS-staged fused QKV GEMM (round-10 validated, unchanged).
__global__ __launch_bounds__(256, 3)
void qkv_lds(const ushort* __restrict__ xb, const ushort* __restrict__ wqb,
             const ushort* __restrict__ wkb, const ushort* __restrict__ wvb,
             const float* __restrict__ bq, const float* __restrict__ bk,
             const float* __restrict__ bv, ushort* __restrict__ qb,
             ushort* __restrict__ kb, ushort* __restrict__ vT) {
  __shared__ char lds[2][20480];  // A[128 rows x 80B] | B at +10240
  const int tid = threadIdx.x;
  const int w = tid >> 6, lane = tid & 63;
  const int l15 = lane & 15, g = lane >> 4;
  const int z = blockIdx.z;
  const ushort* A = (z == 2) ? wvb : xb;
  const ushort* B = (z == 0) ? wqb : (z == 1) ? wkb : xb;
  const float* bias = (z == 0) ? bq : (z == 1) ? bk : bv;
  const int M0 = ((z == 2) ? blockIdx.y : blockIdx.x) * 128;
  const int N0 = ((z == 2) ? blockIdx.x : blockIdx.y) * 128;

  const int sr = tid >> 2, sc = tid & 3;
  const ushort* Ag = A + (size_t)(M0 + sr) * 512 + sc * 8;
  const ushort* Bg = B + (size_t)(N0 + sr) * 512 + sc * 8;
  const int wro = sr * 80 + sc * 16;
  uint4 sa0, sa1, sb0, sb1;

#define QSTAGE_LOAD(kc_)                                      \
  sa0 = *(const uint4*)(Ag + (kc_) * 32);                     \
  sa1 = *(const uint4*)(Ag + (size_t)64 * 512 + (kc_) * 32);  \
  sb0 = *(const uint4*)(Bg + (kc_) * 32);                     \
  sb1 = *(const uint4*)(Bg + (size_t)64 * 512 + (kc_) * 32);
#define QSTAGE_WRITE(buf)                                     \
  *(uint4*)&(buf)[wro] = sa0;                                 \
  *(uint4*)&(buf)[wro + 64 * 80] = sa1;                       \
  *(uint4*)&(buf)[10240 + wro] = sb0;                         \
  *(uint4*)&(buf)[10240 + wro + 64 * 80] = sb1;

  const int wm = w >> 1, wn = w & 1;
  const int aro = (wm * 64 + l15) * 80 + g * 16;
  const int bro = 10240 + (wn * 64 + l15) * 80 + g * 16;

  f32x4 acc[4][4];
#pragma unroll
  for (int i = 0; i < 4; ++i)
#pragma unroll
    for (int j = 0; j < 4; ++j) acc[i][j] = (f32x4){0.f, 0.f, 0.f, 0.f};

  QSTAGE_LOAD(0);
  QSTAGE_WRITE(lds[0]);
  __syncthreads();
  int cur = 0;
#pragma unroll 1
  for (int kc = 0; kc < 16; ++kc) {
    if (kc + 1 < 16) { QSTAGE_LOAD(kc + 1); }
    bf16x8 av[4], bv[4];
#pragma unroll
    for (int t = 0; t < 4; ++t) {
      av[t] = *(const bf16x8*)&lds[cur][aro + t * 1280];
      bv[t] = *(const bf16x8*)&lds[cur][bro + t * 1280];
    }
    __builtin_amdgcn_s_setprio(1);
#pragma unroll
    for (int i = 0; i < 4; ++i)
#pragma unroll
      for (int j = 0; j < 4; ++j)
        acc[i][j] = __builtin_amdgcn_mfma_f32_16x16x32_bf16(av[i], bv[j], acc[i][j], 0, 0, 0);
    __builtin_amdgcn_s_setprio(0);
    if (kc + 1 < 16) { QSTAGE_WRITE(lds[cur ^ 1]); }
    __syncthreads();
    cur ^= 1;
  }
#undef QSTAGE_LOAD
#undef QSTAGE_WRITE

  const int M0w = M0 + wm * 64, N0w = N0 + wn * 64;
  if (z < 2) {
    ushort* out = (z == 0) ? qb : kb;
    float bn[4];
#pragma unroll
    for (int nt = 0; nt < 4; ++nt) bn[nt] = bias[N0w + nt * 16 + l15];
#pragma unroll
    for (int mt = 0; mt < 4; ++mt)
#pragma unroll
      for (int nt = 0; nt < 4; ++nt)
#pragma unroll
        for (int r = 0; r < 4; ++r) {
          const int m = M0w + mt * 16 + 4 * g + r;
          const int n = N0w + nt * 16 + l15;
          out[(size_t)m * 512 + n] = f2bf(acc[mt][nt][r] + bn[nt]);
        }
  } else {
#pragma unroll
    for (int mt = 0; mt < 4; ++mt)
#pragma unroll
      for (int r = 0; r < 4; ++r) {
        const int m = M0w + mt * 16 + 4 * g + r;
        const float bm = bias[m];
#pragma unroll
        for (int nt = 0; nt < 4; ++nt) {
          const int tok = N0w + nt * 16 + l15;
          const size_t off = ((size_t)((tok >> 10) * 512 + m)) * 1024 + (tok & 1023);
          vT[off] = f2bf(acc[mt][nt][r] + bm);
        }
      }
  }
}

// LDS-staged output projection, 128x128 tile (round-17 validated).
__global__ __launch_bounds__(256, 3)
void out_lds(const ushort* __restrict__ A, const ushort* __restrict__ B,
             const float* __restrict__ bias, float* __restrict__ out) {
  __shared__ char lds[2][20480];  // A[128 rows x 80B] | B at +10240
  const int tid = threadIdx.x;
  const int w = tid >> 6, lane = tid & 63;
  const int l15 = lane & 15, g = lane >> 4;
  const int M0 = blockIdx.x * 128, N0 = blockIdx.y * 128;

  const int sr = tid >> 2, sc = tid & 3;
  const ushort* Ag = A + (size_t)(M0 + sr) * 512 + sc * 8;
  const ushort* Bg = B + (size_t)(N0 + sr) * 512 + sc * 8;
  const int wro = sr * 80 + sc * 16;
  uint4 sa0, sa1, sb0, sb1;

#define OSTAGE_LOAD(kc_)                                      \
  sa0 = *(const uint4*)(Ag + (kc_) * 32);                     \
  sa1 = *(const uint4*)(Ag + (size_t)64 * 512 + (kc_) * 32);  \
  sb0 = *(const uint4*)(Bg + (kc_) * 32);                     \
  sb1 = *(const uint4*)(Bg + (size_t)64 * 512 + (kc_) * 32);
#define OSTAGE_WRITE(buf)                                     \
  *(uint4*)&(buf)[wro] = sa0;                                 \
  *(uint4*)&(buf)[wro + 64 * 80] = sa1;                       \
  *(uint4*)&(buf)[10240 + wro] = sb0;                         \
  *(uint4*)&(buf)[10240 + wro + 64 * 80] = sb1;

  const int wm = w >> 1, wn = w & 1;
  const int aro = (wm * 64 + l15) * 80 + g * 16;
  const int bro = 10240 + (wn * 64 + l15) * 80 + g * 16;

  f32x4 acc[4][4];
#pragma unroll
  for (int i = 0; i < 4; ++i)
#pragma unroll
    for (int j = 0; j < 4; ++j) acc[i][j] = (f32x4){0.f, 0.f, 0.f, 0.f};

  OSTAGE_LOAD(0);
  OSTAGE_WRITE(lds[0]);
  __syncthreads();
  int cur = 0;
#pragma unroll 1
  for (int kc = 0; kc < 16; ++kc) {
    if (kc + 1 < 16) { OSTAGE_LOAD(kc + 1); }
    bf16x8 av[4], bv[4];
#pragma unroll
    for (int t = 0; t < 4; ++t) {
      av[t] = *(const bf16x8*)&lds[cur][aro + t * 1280];
      bv[t] = *(const bf16x8*)&lds[cur][bro + t * 1280];
    }
    __builtin_amdgcn_s_setprio(1);
#pragma unroll
    for (int i = 0; i < 4; ++i)
#pragma unroll
      for (int j = 0; j < 4; ++j)
        acc[i][j] = __builtin_amdgcn_mfma_f32_16x16x32_bf16(av[i], bv[j], acc[i][j], 0, 0, 0);
    __builtin_amdgcn_s_setprio(0);
    if (kc + 1 < 16) { OSTAGE_WRITE(lds[cur ^ 1]); }
    __syncthreads();
    cur ^= 1;
  }
#undef OSTAGE_LOAD
#undef OSTAGE_WRITE

  const int M0w = M0 + wm * 64, N0w = N0 + wn * 64;
  float bn[4];
#pragma unroll
  for (int nt = 0; nt < 4; ++nt) bn[nt] = bias[N0w + nt * 16 + l15];
#pragma unroll
  for (int mt = 0; mt < 4; ++mt)
#pragma unroll
    for (int nt = 0; nt < 4; ++nt)
#pragma unroll
      for (int r = 0; r < 4; ++r) {
        const int m = M0w + mt * 16 + 4 * g + r;
        const int n = N0w + nt * 16 + l15;
        out[(size_t)m * 512 + n] = acc[mt][nt][r] + bn[nt];
      }
}

// Cooperative flash attention (R12/R17 body) with ONE change: V is no longer
// LDS-staged. Per-(b,h) K+V = 256KB; per XCD (one batch) 2MB -> L2-resident,
// so vf fragments load directly from global (L2 hit), issued early so latency
// hides under QK^T + softmax. LDS drops 40KB -> 24KB => up to 6 blocks/CU
// (was 4). K keeps the swizzled LDS path (needed for the B-operand layout).
__global__ __launch_bounds__(256, 2)
void attn_mfma(const ushort* __restrict__ qb, const ushort* __restrict__ kb,
               const ushort* __restrict__ vT, const int* __restrict__ tbm,
               const float* __restrict__ temb, const int* __restrict__ lens,
               ushort* __restrict__ ab) {
  __shared__ char kv[2][8192];    // [buf][K 8KB], swizzled
  __shared__ char pbuf[4][2048];  // per-wave P tile
  const int tid = threadIdx.x;
  const int w = tid >> 6;
  const int lane = tid & 63;
  const int l15 = lane & 15, g = lane >> 4;
  const int b = blockIdx.x, h = blockIdx.y;
  const int qg = 15 - blockIdx.z;    // LPT: longest first
  const int len = lens[b];
  const int qbase = qg * 64 + 16 * w;

  const float te_src = temb[(lane & 7) * N_HEADS + h] * 1.44269504f;

  const int r0 = tid >> 3, c0l = tid & 7;
  const size_t kgrow = (size_t)(b * L_SEQ) * HID_DIM + h * HEAD_DIM + c0l * 8;
  const int so0 = (tid * 16) ^ ((r0 & 7) << 4);
  const int so1 = so0 + 4096;
  uint4 skA, skB;

#define STAGE_LOAD(kc_)                                                      \
  skA = *(const uint4*)(kb + kgrow + (size_t)((kc_) + r0) * HID_DIM);        \
  skB = *(const uint4*)(kb + kgrow + (size_t)((kc_) + r0 + 32) * HID_DIM);

#define STAGE_WRITE(dst)                                                     \
  *(uint4*)&(dst)[so0] = skA;                                                \
  *(uint4*)&(dst)[so1] = skB;

  bf16x8 qf[2];
  {
    const ushort* qr = qb + (size_t)(b * L_SEQ + qbase + l15) * HID_DIM + h * HEAD_DIM + 8 * g;
    qf[0] = *(const bf16x8*)(qr);
    qf[1] = *(const bf16x8*)(qr + 32);
  }
  const ushort* vbase = vT + (size_t)((b * 8 + h) * 64 + l15) * L_SEQ + 8 * g;

  f32x4 O[4];
#pragma unroll
  for (int ct = 0; ct < 4; ++ct) O[ct] = (f32x4){0.f, 0.f, 0.f, 0.f};
  float ssum[4] = {0.f, 0.f, 0.f, 0.f};
  int tb_[4][4];

  const int lenc = (len - 1) >> 6;
  const int nch = (qg * 64 < len) ? ((qg < lenc ? qg : lenc) + 1) : 0;
  const int* tbq = tbm + (size_t)(b * L_SEQ + qbase) * L_SEQ;

  if (nch > 0) {
    STAGE_LOAD(0);
    STAGE_WRITE(kv[0]);
  }
  __syncthreads();

  int cur = 0;
#pragma unroll 1
  for (int c = 0; c < nch; ++c) {
    const int kc = c * 64;
    // tb indices for this chunk (scattered dword loads, issued first)
#pragma unroll
    for (int kt = 0; kt < 4; ++kt)
#pragma unroll
      for (int r = 0; r < 4; ++r)
        tb_[kt][r] = tbq[(size_t)(4 * g + r) * L_SEQ + kc + 16 * kt + l15];
    // V fragments straight from global (L2-resident) — issued early so the
    // ~200cy L2 latency hides under kf LDS reads + QK^T + softmax
    bf16x8 vf[2][4];
#pragma unroll
    for (int kblk = 0; kblk < 2; ++kblk)
#pragma unroll
      for (int ct = 0; ct < 4; ++ct)
        vf[kblk][ct] = *(const bf16x8*)(vbase + (size_t)(16 * ct) * L_SEQ + kc + 32 * kblk);
    // next chunk's K global loads in flight under this chunk's compute
    if (c + 1 < nch) { STAGE_LOAD(kc + 64); }

    // K fragments from LDS, then QK^T (kf dead after this)
    bf16x8 kf[4][2];
#pragma unroll
    for (int kt = 0; kt < 4; ++kt)
#pragma unroll
      for (int db = 0; db < 2; ++db) {
        const int off = ((2048 * kt + 128 * l15 + 16 * (g + 4 * db)) ^ ((l15 & 7) << 4));
        kf[kt][db] = *(const bf16x8*)&kv[cur][off];
      }
    f32x4 s[4];
    __builtin_amdgcn_s_setprio(1);
#pragma unroll
    for (int kt = 0; kt < 4; ++kt) {
      s[kt] = (f32x4){0.f, 0.f, 0.f, 0.f};
      s[kt] = __builtin_amdgcn_mfma_f32_16x16x32_bf16(qf[0], kf[kt][0], s[kt], 0, 0, 0);
      s[kt] = __builtin_amdgcn_mfma_f32_16x16x32_bf16(qf[1], kf[kt][1], s[kt], 0, 0, 0);
    }
    __builtin_amdgcn_s_setprio(0);

    // softmax: bias lookup, exp2, mask, bf16 pack into pbuf
#pragma unroll
    for (int kt = 0; kt < 4; ++kt) {
      const int kg = kc + 16 * kt + l15;
#pragma unroll
      for (int r = 0; r < 4; ++r) {
        const int lr = 4 * g + r;
        const int qgr = qbase + lr;
        const float te2 = __int_as_float(
            __builtin_amdgcn_ds_bpermute(tb_[kt][r] << 2, __float_as_int(te_src)));
        float pp = exp2f(fmaf(s[kt][r], 0.18033688f, te2));
        pp = (kg <= qgr && qgr < len) ? pp : 0.0f;
        ssum[r] += pp;
        const int off = ((lr * 128 + (16 * kt + l15) * 2) ^ ((lr & 7) << 4));
        *(ushort*)&pbuf[w][off] = f2bf(pp);
      }
    }

    // PV
#pragma unroll
    for (int kblk = 0; kblk < 2; ++kblk) {
      const int off = ((l15 * 128 + kblk * 64 + 16 * g) ^ ((l15 & 7) << 4));
      const bf16x8 pf = *(const bf16x8*)(&pbuf[w][off]);
      __builtin_amdgcn_s_setprio(1);
#pragma unroll
      for (int ct = 0; ct < 4; ++ct)
        O[ct] = __builtin_amdgcn_mfma_f32_16x16x32_bf16(pf, vf[kblk][ct], O[ct], 0, 0, 0);
      __builtin_amdgcn_s_setprio(0);
    }

    if (c + 1 < nch) { STAGE_WRITE(kv[cur ^ 1]); }
    __syncthreads();
    cur ^= 1;
  }
#undef STAGE_LOAD
#undef STAGE_WRITE

#pragma unroll
  for (int m = 1; m <= 8; m <<= 1) {
#pragma unroll
    for (int r = 0; r < 4; ++r) ssum[r] += __shfl_xor(ssum[r], m, 64);
  }
#pragma unroll
  for (int ct = 0; ct < 4; ++ct)
#pragma unroll
    for (int r = 0; r < 4; ++r) {
      const int qgr = qbase + 4 * g + r;
      const float inv = (qgr < len && nch > 0) ? 1.0f / ssum[r] : 0.0f;
      ab[(size_t)(b * L_SEQ + qgr) * HID_DIM + h * HEAD_DIM + 16 * ct + l15] =
          f2bf(O[ct][r] * inv);
    }
}

extern "C" void kernel_launch(void* const* d_in, const int* in_sizes, int n_in,
                              void* d_out, int out_size, void* d_ws, size_t ws_size,
                              hipStream_t stream) {
  const float* x    = (const float*)d_in[0];
  const int*   tbm  = (const int*)d_in[1];
  // d_in[2] = causal_mask: deterministic triu(k=1) -> handled analytically
  const uint8_t* pm = (const uint8_t*)d_in[3];
  const float* Wq = (const float*)d_in[4];
  const float* bq = (const float*)d_in[5];
  const float* Wk = (const float*)d_in[6];
  const float* bk = (const float*)d_in[7];
  const float* Wv = (const float*)d_in[8];
  const float* bv = (const float*)d_in[9];
  const float* Wo = (const float*)d_in[10];
  const float* bo = (const float*)d_in[11];
  const float* temb = (const float*)d_in[12];
  float* out = (float*)d_out;

  const size_t NTOK = (size_t)BATCH * L_SEQ * HID_DIM;  // 4,194,304
  const size_t NW = 262144;
  ushort* ab  = (ushort*)d_ws;        // bf16 attention output [8192][512]
  ushort* xb  = ab + NTOK;            // bf16 x
  ushort* wqb = xb + NTOK;
  ushort* wkb = wqb + NW;
  ushort* wvb = wkb + NW;
  ushort* wob = wvb + NW;
  ushort* qb  = wob + NW;             // bf16 Q [tok][512]
  ushort* kb  = qb + NTOK;            // bf16 K [tok][512]
  ushort* vT  = kb + NTOK;            // bf16 V^T [b*8+h][64][1024]
  int* lens   = (int*)(vT + NTOK);

  prep_lens<<<2568, 256, 0, stream>>>(x, Wq, Wk, Wv, Wo, pm, xb, lens);
  qkv_lds<<<dim3(64, 4, 3), 256, 0, stream>>>(xb, wqb, wkb, wvb, bq, bk, bv, qb, kb, vT);
  attn_mfma<<<dim3(8, 8, 16), 256, 0, stream>>>(qb, kb, vT, tbm, temb, lens, ab);
  out_lds<<<dim3(64, 4), 256, 0, stream>>>(ab, wob, bo, out);
}

// Round 19
// 78.929 us; speedup vs baseline: 1.1551x; 1.1551x over previous
//
#include <hip/hip_runtime.h>
#include <hip/hip_bf16.h>
#include <cstdint>

#define L_SEQ 1024
#define HID_DIM 512
#define N_HEADS 8
#define HEAD_DIM 64
#define BATCH 8

typedef __attribute__((ext_vector_type(8))) short bf16x8;
typedef __attribute__((ext_vector_type(4))) float f32x4;

__device__ __forceinline__ ushort f2bf(float v) {
  __hip_bfloat16 hb = __float2bfloat16(v);
  return *(ushort*)&hb;
}

// Fused: blocks <2560 convert f32->bf16 (x then Wq,Wk,Wv,Wo); blocks >=2560
// compute lens[b] (layout-detecting padding_mask row count, see round 3).
__global__ __launch_bounds__(256)
void prep_lens(const float* __restrict__ x, const float* __restrict__ Wq,
               const float* __restrict__ Wk, const float* __restrict__ Wv,
               const float* __restrict__ Wo, const uint8_t* __restrict__ pm,
               ushort* __restrict__ dst, int* __restrict__ lens) {
  if (blockIdx.x >= 2560) {
    __shared__ int flag;
    __shared__ int part[256];
    const int b = blockIdx.x - 2560, tid = threadIdx.x;
    if (tid == 0) flag = 0;
    __syncthreads();
    const unsigned* pw = (const unsigned*)pm;
    unsigned any = 0;
    for (int i = tid; i < 2048; i += 256) any |= (pw[i] > 1u);
    if (any) flag = 1;
    __syncthreads();
    int c = 0;
    if (flag) {
      unsigned v = pw[b * 256 + tid];
      c = (int)((v & 0xFFu) == 0) + (int)(((v >> 8) & 0xFFu) == 0) +
          (int)(((v >> 16) & 0xFFu) == 0) + (int)(((v >> 24) & 0xFFu) == 0);
    } else {
      const int* pi = (const int*)pm;
      c = (int)(pi[b * 1024 + tid * 4 + 0] == 0) + (int)(pi[b * 1024 + tid * 4 + 1] == 0) +
          (int)(pi[b * 1024 + tid * 4 + 2] == 0) + (int)(pi[b * 1024 + tid * 4 + 3] == 0);
    }
    part[tid] = c;
    __syncthreads();
    for (int s = 128; s > 0; s >>= 1) {
      if (tid < s) part[tid] += part[tid + s];
      __syncthreads();
    }
    if (tid == 0) lens[b] = part[0];
    return;
  }
  const size_t gid = (size_t)blockIdx.x * 256 + threadIdx.x;
  const size_t e = gid * 8;
  const float* src;
  size_t loc;
  if (e < 4194304) {
    src = x; loc = e;
  } else {
    const size_t r = e - 4194304;
    const int wsel = (int)(r >> 18);
    loc = r & 262143;
    src = (wsel == 0) ? Wq : (wsel == 1) ? Wk : (wsel == 2) ? Wv : Wo;
  }
  float4 v0 = *(const float4*)(src + loc);
  float4 v1 = *(const float4*)(src + loc + 4);
  ushort u[8];
  u[0] = f2bf(v0.x); u[1] = f2bf(v0.y); u[2] = f2bf(v0.z); u[3] = f2bf(v0.w);
  u[4] = f2bf(v1.x); u[5] = f2bf(v1.y); u[6] = f2bf(v1.z); u[7] = f2bf(v1.w);
  *(uint4*)(dst + e) = *(uint4*)u;
}

// ---------------------------------------------------------------------------
// LDS-staged fused QKV GEMM (round-10 validated, unchanged).
__global__ __launch_bounds__(256, 3)
void qkv_lds(const ushort* __restrict__ xb, const ushort* __restrict__ wqb,
             const ushort* __restrict__ wkb, const ushort* __restrict__ wvb,
             const float* __restrict__ bq, const float* __restrict__ bk,
             const float* __restrict__ bv, ushort* __restrict__ qb,
             ushort* __restrict__ kb, ushort* __restrict__ vT) {
  __shared__ char lds[2][20480];  // A[128 rows x 80B] | B at +10240
  const int tid = threadIdx.x;
  const int w = tid >> 6, lane = tid & 63;
  const int l15 = lane & 15, g = lane >> 4;
  const int z = blockIdx.z;
  const ushort* A = (z == 2) ? wvb : xb;
  const ushort* B = (z == 0) ? wqb : (z == 1) ? wkb : xb;
  const float* bias = (z == 0) ? bq : (z == 1) ? bk : bv;
  const int M0 = ((z == 2) ? blockIdx.y : blockIdx.x) * 128;
  const int N0 = ((z == 2) ? blockIdx.x : blockIdx.y) * 128;

  const int sr = tid >> 2, sc = tid & 3;
  const ushort* Ag = A + (size_t)(M0 + sr) * 512 + sc * 8;
  const ushort* Bg = B + (size_t)(N0 + sr) * 512 + sc * 8;
  const int wro = sr * 80 + sc * 16;
  uint4 sa0, sa1, sb0, sb1;

#define QSTAGE_LOAD(kc_)                                      \
  sa0 = *(const uint4*)(Ag + (kc_) * 32);                     \
  sa1 = *(const uint4*)(Ag + (size_t)64 * 512 + (kc_) * 32);  \
  sb0 = *(const uint4*)(Bg + (kc_) * 32);                     \
  sb1 = *(const uint4*)(Bg + (size_t)64 * 512 + (kc_) * 32);
#define QSTAGE_WRITE(buf)                                     \
  *(uint4*)&(buf)[wro] = sa0;                                 \
  *(uint4*)&(buf)[wro + 64 * 80] = sa1;                       \
  *(uint4*)&(buf)[10240 + wro] = sb0;                         \
  *(uint4*)&(buf)[10240 + wro + 64 * 80] = sb1;

  const int wm = w >> 1, wn = w & 1;
  const int aro = (wm * 64 + l15) * 80 + g * 16;
  const int bro = 10240 + (wn * 64 + l15) * 80 + g * 16;

  f32x4 acc[4][4];
#pragma unroll
  for (int i = 0; i < 4; ++i)
#pragma unroll
    for (int j = 0; j < 4; ++j) acc[i][j] = (f32x4){0.f, 0.f, 0.f, 0.f};

  QSTAGE_LOAD(0);
  QSTAGE_WRITE(lds[0]);
  __syncthreads();
  int cur = 0;
#pragma unroll 1
  for (int kc = 0; kc < 16; ++kc) {
    if (kc + 1 < 16) { QSTAGE_LOAD(kc + 1); }
    bf16x8 av[4], bv[4];
#pragma unroll
    for (int t = 0; t < 4; ++t) {
      av[t] = *(const bf16x8*)&lds[cur][aro + t * 1280];
      bv[t] = *(const bf16x8*)&lds[cur][bro + t * 1280];
    }
    __builtin_amdgcn_s_setprio(1);
#pragma unroll
    for (int i = 0; i < 4; ++i)
#pragma unroll
      for (int j = 0; j < 4; ++j)
        acc[i][j] = __builtin_amdgcn_mfma_f32_16x16x32_bf16(av[i], bv[j], acc[i][j], 0, 0, 0);
    __builtin_amdgcn_s_setprio(0);
    if (kc + 1 < 16) { QSTAGE_WRITE(lds[cur ^ 1]); }
    __syncthreads();
    cur ^= 1;
  }
#undef QSTAGE_LOAD
#undef QSTAGE_WRITE

  const int M0w = M0 + wm * 64, N0w = N0 + wn * 64;
  if (z < 2) {
    ushort* out = (z == 0) ? qb : kb;
    float bn[4];
#pragma unroll
    for (int nt = 0; nt < 4; ++nt) bn[nt] = bias[N0w + nt * 16 + l15];
#pragma unroll
    for (int mt = 0; mt < 4; ++mt)
#pragma unroll
      for (int nt = 0; nt < 4; ++nt)
#pragma unroll
        for (int r = 0; r < 4; ++r) {
          const int m = M0w + mt * 16 + 4 * g + r;
          const int n = N0w + nt * 16 + l15;
          out[(size_t)m * 512 + n] = f2bf(acc[mt][nt][r] + bn[nt]);
        }
  } else {
#pragma unroll
    for (int mt = 0; mt < 4; ++mt)
#pragma unroll
      for (int r = 0; r < 4; ++r) {
        const int m = M0w + mt * 16 + 4 * g + r;
        const float bm = bias[m];
#pragma unroll
        for (int nt = 0; nt < 4; ++nt) {
          const int tok = N0w + nt * 16 + l15;
          const size_t off = ((size_t)((tok >> 10) * 512 + m)) * 1024 + (tok & 1023);
          vT[off] = f2bf(acc[mt][nt][r] + bm);
        }
      }
  }
}

// LDS-staged output projection, 128x128 tile (round-17 validated).
__global__ __launch_bounds__(256, 3)
void out_lds(const ushort* __restrict__ A, const ushort* __restrict__ B,
             const float* __restrict__ bias, float* __restrict__ out) {
  __shared__ char lds[2][20480];  // A[128 rows x 80B] | B at +10240
  const int tid = threadIdx.x;
  const int w = tid >> 6, lane = tid & 63;
  const int l15 = lane & 15, g = lane >> 4;
  const int M0 = blockIdx.x * 128, N0 = blockIdx.y * 128;

  const int sr = tid >> 2, sc = tid & 3;
  const ushort* Ag = A + (size_t)(M0 + sr) * 512 + sc * 8;
  const ushort* Bg = B + (size_t)(N0 + sr) * 512 + sc * 8;
  const int wro = sr * 80 + sc * 16;
  uint4 sa0, sa1, sb0, sb1;

#define OSTAGE_LOAD(kc_)                                      \
  sa0 = *(const uint4*)(Ag + (kc_) * 32);                     \
  sa1 = *(const uint4*)(Ag + (size_t)64 * 512 + (kc_) * 32);  \
  sb0 = *(const uint4*)(Bg + (kc_) * 32);                     \
  sb1 = *(const uint4*)(Bg + (size_t)64 * 512 + (kc_) * 32);
#define OSTAGE_WRITE(buf)                                     \
  *(uint4*)&(buf)[wro] = sa0;                                 \
  *(uint4*)&(buf)[wro + 64 * 80] = sa1;                       \
  *(uint4*)&(buf)[10240 + wro] = sb0;                         \
  *(uint4*)&(buf)[10240 + wro + 64 * 80] = sb1;

  const int wm = w >> 1, wn = w & 1;
  const int aro = (wm * 64 + l15) * 80 + g * 16;
  const int bro = 10240 + (wn * 64 + l15) * 80 + g * 16;

  f32x4 acc[4][4];
#pragma unroll
  for (int i = 0; i < 4; ++i)
#pragma unroll
    for (int j = 0; j < 4; ++j) acc[i][j] = (f32x4){0.f, 0.f, 0.f, 0.f};

  OSTAGE_LOAD(0);
  OSTAGE_WRITE(lds[0]);
  __syncthreads();
  int cur = 0;
#pragma unroll 1
  for (int kc = 0; kc < 16; ++kc) {
    if (kc + 1 < 16) { OSTAGE_LOAD(kc + 1); }
    bf16x8 av[4], bv[4];
#pragma unroll
    for (int t = 0; t < 4; ++t) {
      av[t] = *(const bf16x8*)&lds[cur][aro + t * 1280];
      bv[t] = *(const bf16x8*)&lds[cur][bro + t * 1280];
    }
    __builtin_amdgcn_s_setprio(1);
#pragma unroll
    for (int i = 0; i < 4; ++i)
#pragma unroll
      for (int j = 0; j < 4; ++j)
        acc[i][j] = __builtin_amdgcn_mfma_f32_16x16x32_bf16(av[i], bv[j], acc[i][j], 0, 0, 0);
    __builtin_amdgcn_s_setprio(0);
    if (kc + 1 < 16) { OSTAGE_WRITE(lds[cur ^ 1]); }
    __syncthreads();
    cur ^= 1;
  }
#undef OSTAGE_LOAD
#undef OSTAGE_WRITE

  const int M0w = M0 + wm * 64, N0w = N0 + wn * 64;
  float bn[4];
#pragma unroll
  for (int nt = 0; nt < 4; ++nt) bn[nt] = bias[N0w + nt * 16 + l15];
#pragma unroll
  for (int mt = 0; mt < 4; ++mt)
#pragma unroll
    for (int nt = 0; nt < 4; ++nt)
#pragma unroll
      for (int r = 0; r < 4; ++r) {
        const int m = M0w + mt * 16 + 4 * g + r;
        const int n = N0w + nt * 16 + l15;
        out[(size_t)m * 512 + n] = acc[mt][nt][r] + bn[nt];
      }
}

// Cooperative flash attention (R12/R17 verbatim — the validated 40.4 us loop).
// Grid (8 b, 8 h, 16 qg): 1024 blocks, 4/CU by LDS. id%8=b -> XCD locality.
// K AND V LDS-staged double-buffered (full chunk-ahead prefetch distance —
// R18 showed V-from-global exposes L2 latency: prefetch distance > residency).
__global__ __launch_bounds__(256, 2)
void attn_mfma(const ushort* __restrict__ qb, const ushort* __restrict__ kb,
               const ushort* __restrict__ vT, const int* __restrict__ tbm,
               const float* __restrict__ temb, const int* __restrict__ lens,
               ushort* __restrict__ ab) {
  __shared__ char kv[2][16384];   // [buf][K 8KB | V 8KB], swizzled
  __shared__ char pbuf[4][2048];  // per-wave P tile
  const int tid = threadIdx.x;
  const int w = tid >> 6;
  const int lane = tid & 63;
  const int l15 = lane & 15, g = lane >> 4;
  const int b = blockIdx.x, h = blockIdx.y;
  const int qg = 15 - blockIdx.z;    // LPT: longest first
  const int len = lens[b];
  const int qbase = qg * 64 + 16 * w;

  const float te_src = temb[(lane & 7) * N_HEADS + h] * 1.44269504f;

  const int r0 = tid >> 3, c0l = tid & 7;
  const size_t kgrow = (size_t)(b * L_SEQ) * HID_DIM + h * HEAD_DIM + c0l * 8;
  const size_t vgrow = (size_t)((b * 8 + h) * 64 + r0) * L_SEQ + c0l * 8;
  const int so0 = (tid * 16) ^ ((r0 & 7) << 4);
  const int so1 = so0 + 4096;
  uint4 skA, skB, svA, svB;

#define STAGE_LOAD(kc_)                                                      \
  skA = *(const uint4*)(kb + kgrow + (size_t)((kc_) + r0) * HID_DIM);        \
  skB = *(const uint4*)(kb + kgrow + (size_t)((kc_) + r0 + 32) * HID_DIM);   \
  svA = *(const uint4*)(vT + vgrow + (kc_));                                 \
  svB = *(const uint4*)(vT + vgrow + 32 * L_SEQ + (kc_));

#define STAGE_WRITE(dst)                                                     \
  *(uint4*)&(dst)[so0] = skA;                                                \
  *(uint4*)&(dst)[so1] = skB;                                                \
  *(uint4*)&(dst)[8192 + so0] = svA;                                         \
  *(uint4*)&(dst)[8192 + so1] = svB;

  bf16x8 qf[2];
  {
    const ushort* qr = qb + (size_t)(b * L_SEQ + qbase + l15) * HID_DIM + h * HEAD_DIM + 8 * g;
    qf[0] = *(const bf16x8*)(qr);
    qf[1] = *(const bf16x8*)(qr + 32);
  }

  f32x4 O[4];
#pragma unroll
  for (int ct = 0; ct < 4; ++ct) O[ct] = (f32x4){0.f, 0.f, 0.f, 0.f};
  float ssum[4] = {0.f, 0.f, 0.f, 0.f};
  int tb_[4][4];

  const int lenc = (len - 1) >> 6;
  const int nch = (qg * 64 < len) ? ((qg < lenc ? qg : lenc) + 1) : 0;
  const int* tbq = tbm + (size_t)(b * L_SEQ + qbase) * L_SEQ;

  if (nch > 0) {
    STAGE_LOAD(0);
    STAGE_WRITE(kv[0]);
  }
  __syncthreads();

  int cur = 0;
#pragma unroll 1
  for (int c = 0; c < nch; ++c) {
    const int kc = c * 64;
    // tb indices for this chunk (scattered dword loads, issued first)
#pragma unroll
    for (int kt = 0; kt < 4; ++kt)
#pragma unroll
      for (int r = 0; r < 4; ++r)
        tb_[kt][r] = tbq[(size_t)(4 * g + r) * L_SEQ + kc + 16 * kt + l15];
    // next chunk's K/V global loads in flight under this chunk's compute
    if (c + 1 < nch) { STAGE_LOAD(kc + 64); }

    // K fragments from LDS, then QK^T (kf dead after this)
    bf16x8 kf[4][2];
#pragma unroll
    for (int kt = 0; kt < 4; ++kt)
#pragma unroll
      for (int db = 0; db < 2; ++db) {
        const int off = ((2048 * kt + 128 * l15 + 16 * (g + 4 * db)) ^ ((l15 & 7) << 4));
        kf[kt][db] = *(const bf16x8*)&kv[cur][off];
      }
    f32x4 s[4];
    __builtin_amdgcn_s_setprio(1);
#pragma unroll
    for (int kt = 0; kt < 4; ++kt) {
      s[kt] = (f32x4){0.f, 0.f, 0.f, 0.f};
      s[kt] = __builtin_amdgcn_mfma_f32_16x16x32_bf16(qf[0], kf[kt][0], s[kt], 0, 0, 0);
      s[kt] = __builtin_amdgcn_mfma_f32_16x16x32_bf16(qf[1], kf[kt][1], s[kt], 0, 0, 0);
    }
    __builtin_amdgcn_s_setprio(0);

    // V fragments (LDS reads overlap softmax VALU below)
    bf16x8 vf[2][4];
#pragma unroll
    for (int kblk = 0; kblk < 2; ++kblk)
#pragma unroll
      for (int ct = 0; ct < 4; ++ct) {
        const int off = 8192 + ((2048 * ct + 128 * l15 + 16 * (4 * kblk + g)) ^ ((l15 & 7) << 4));
        vf[kblk][ct] = *(const bf16x8*)&kv[cur][off];
      }

    // softmax: bias lookup, exp2, mask, bf16 pack into pbuf
#pragma unroll
    for (int kt = 0; kt < 4; ++kt) {
      const int kg = kc + 16 * kt + l15;
#pragma unroll
      for (int r = 0; r < 4; ++r) {
        const int lr = 4 * g + r;
        const int qgr = qbase + lr;
        const float te2 = __int_as_float(
            __builtin_amdgcn_ds_bpermute(tb_[kt][r] << 2, __float_as_int(te_src)));
        float pp = exp2f(fmaf(s[kt][r], 0.18033688f, te2));
        pp = (kg <= qgr && qgr < len) ? pp : 0.0f;
        ssum[r] += pp;
        const int off = ((lr * 128 + (16 * kt + l15) * 2) ^ ((lr & 7) << 4));
        *(ushort*)&pbuf[w][off] = f2bf(pp);
      }
    }

    // PV
#pragma unroll
    for (int kblk = 0; kblk < 2; ++kblk) {
      const int off = ((l15 * 128 + kblk * 64 + 16 * g) ^ ((l15 & 7) << 4));
      const bf16x8 pf = *(const bf16x8*)(&pbuf[w][off]);
      __builtin_amdgcn_s_setprio(1);
#pragma unroll
      for (int ct = 0; ct < 4; ++ct)
        O[ct] = __builtin_amdgcn_mfma_f32_16x16x32_bf16(pf, vf[kblk][ct], O[ct], 0, 0, 0);
      __builtin_amdgcn_s_setprio(0);
    }

    if (c + 1 < nch) { STAGE_WRITE(kv[cur ^ 1]); }
    __syncthreads();
    cur ^= 1;
  }
#undef STAGE_LOAD
#undef STAGE_WRITE

#pragma unroll
  for (int m = 1; m <= 8; m <<= 1) {
#pragma unroll
    for (int r = 0; r < 4; ++r) ssum[r] += __shfl_xor(ssum[r], m, 64);
  }
#pragma unroll
  for (int ct = 0; ct < 4; ++ct)
#pragma unroll
    for (int r = 0; r < 4; ++r) {
      const int qgr = qbase + 4 * g + r;
      const float inv = (qgr < len && nch > 0) ? 1.0f / ssum[r] : 0.0f;
      ab[(size_t)(b * L_SEQ + qgr) * HID_DIM + h * HEAD_DIM + 16 * ct + l15] =
          f2bf(O[ct][r] * inv);
    }
}

extern "C" void kernel_launch(void* const* d_in, const int* in_sizes, int n_in,
                              void* d_out, int out_size, void* d_ws, size_t ws_size,
                              hipStream_t stream) {
  const float* x    = (const float*)d_in[0];
  const int*   tbm  = (const int*)d_in[1];
  // d_in[2] = causal_mask: deterministic triu(k=1) -> handled analytically
  const uint8_t* pm = (const uint8_t*)d_in[3];
  const float* Wq = (const float*)d_in[4];
  const float* bq = (const float*)d_in[5];
  const float* Wk = (const float*)d_in[6];
  const float* bk = (const float*)d_in[7];
  const float* Wv = (const float*)d_in[8];
  const float* bv = (const float*)d_in[9];
  const float* Wo = (const float*)d_in[10];
  const float* bo = (const float*)d_in[11];
  const float* temb = (const float*)d_in[12];
  float* out = (float*)d_out;

  const size_t NTOK = (size_t)BATCH * L_SEQ * HID_DIM;  // 4,194,304
  const size_t NW = 262144;
  ushort* ab  = (ushort*)d_ws;        // bf16 attention output [8192][512]
  ushort* xb  = ab + NTOK;            // bf16 x
  ushort* wqb = xb + NTOK;
  ushort* wkb = wqb + NW;
  ushort* wvb = wkb + NW;
  ushort* wob = wvb + NW;
  ushort* qb  = wob + NW;             // bf16 Q [tok][512]
  ushort* kb  = qb + NTOK;            // bf16 K [tok][512]
  ushort* vT  = kb + NTOK;            // bf16 V^T [b*8+h][64][1024]
  int* lens   = (int*)(vT + NTOK);

  prep_lens<<<2568, 256, 0, stream>>>(x, Wq, Wk, Wv, Wo, pm, xb, lens);
  qkv_lds<<<dim3(64, 4, 3), 256, 0, stream>>>(xb, wqb, wkb, wvb, bq, bk, bv, qb, kb, vT);
  attn_mfma<<<dim3(8, 8, 16), 256, 0, stream>>>(qb, kb, vT, tbm, temb, lens, ab);
  out_lds<<<dim3(64, 4), 256, 0, stream>>>(ab, wob, bo, out);
}